// Round 4
// baseline (106.768 us; speedup 1.0000x reference)
//
#include <hip/hip_runtime.h>
#include <stdint.h>

// Problem constants (from reference)
#define IN_SCALE 23
#define DDIM 529                         // 23*23
#define BATCH 2
#define BITS 32
#define HDC 512
#define ROW (BITS * HDC)                 // 16384 floats per (c,bb,d)
#define NNZ_REGION (DDIM * HDC)          // 270848 — all indices land here (bb=0, d<=16)
#define SMALL (5 * BATCH * DDIM)         // 5290 small output floats (== 2 mod 4)
#define BIN_PER_OUT (BATCH * DDIM * ROW) // 17334272
#define BIN_PER_B   (DDIM * ROW)         // 8667136

typedef float f32x4 __attribute__((ext_vector_type(4)));  // builtin-compatible vec4

// ---------------------------------------------------------------------------
// Kernel A: pure bit-pattern stream, mask-free, branch-free.
// One block per (c, bb, d): computes scalar v, writes out[blk]=v (small outs),
// then 16384 floats where element e has value bit_{e/512}(v).
// Thread t's k-th float4 covers elements e0=2+4(t+256k); bit index j=(e0>>9)
// advances by exactly 2 per k; chunk-crossing ((e0&511)==510) is k-invariant
// (lanes 127,255 only) -> running shift, ~6 VALU per 16B store.
// ---------------------------------------------------------------------------
__global__ __launch_bounds__(256) void bins_pattern(const float* __restrict__ data,
                                                    const float* __restrict__ structure,
                                                    const float* __restrict__ params,
                                                    float* __restrict__ out) {
    int blk = blockIdx.x;                 // 0..5289 == small-output flat index
    int c   = blk / (BATCH * DDIM);
    int rem = blk % (BATCH * DDIM);
    int bb  = rem / DDIM;
    int d   = rem % DDIM;

    float v;
    if (c < 4) {
        v = data[bb * (4 * DDIM) + c * DDIM + d];   // [B][4*23][23]
    } else {
        v = structure[bb * DDIM + d] * params[d];
    }
    const unsigned x = (unsigned)__float_as_int(v);

    long long base = (long long)SMALL + (long long)c * BIN_PER_OUT
                   + (long long)bb * BIN_PER_B + (long long)d * ROW;
    float* o = out + base;                // base == 2 (mod 4)

    const int t = threadIdx.x;
    if (t == 0) {
        out[blk] = v;                     // fused small output
        float f0 = (float)(x & 1u);       // head: e=0,1 (bit 0)
        *(float2*)o = make_float2(f0, f0);
    } else if (t == 1) {
        float f31 = (float)((x >> 31) & 1u);  // tail: e=16382,16383 (bit 31)
        *(float2*)(o + ROW - 2) = make_float2(f31, f31);
    }

    // middle: 4095 aligned float4 at o+2
    f32x4* om = (f32x4*)(o + 2);
    const int e0     = 4 * t + 2;
    const int jbase  = e0 >> 9;                     // 0 or 1
    const int cross  = ((e0 & 511) == 510) ? 1 : 0; // lanes t=127,255 only
    unsigned xs = x >> jbase;
    #pragma unroll
    for (int k = 0; k < 16; ++k) {
        int q = t + (k << 8);
        if (q < 4095) {                   // masks only lane 255 @ k=15
            float fa = (float)(xs & 1u);
            float fb = (float)((xs >> cross) & 1u);  // elems 2,3 may be next bit
            f32x4 w = {fa, fa, fb, fb};
            __builtin_nontemporal_store(w, &om[q]);
        }
        xs >>= 2;                         // bit index advances 2 per k
    }
}

// ---------------------------------------------------------------------------
// Kernel B: sparse fixup. For each nonzero index p (< NNZ_REGION, bb=0 frame),
// the reference XORs the pattern with 1 -> overwrite with bit^1 for all 5
// channels. Duplicates are idempotent. ~677k scattered 4B stores into ~5.4 MB.
// ---------------------------------------------------------------------------
__global__ __launch_bounds__(256) void bins_fixup(const int* __restrict__ idx, int n,
                                                  const float* __restrict__ data,
                                                  const float* __restrict__ structure,
                                                  const float* __restrict__ params,
                                                  float* __restrict__ out) {
    int i = blockIdx.x * blockDim.x + threadIdx.x;
    if (i >= n) return;
    unsigned p = (unsigned)idx[i];
    if (p >= NNZ_REGION) return;
    int d = p >> 14;          // p / 16384
    int j = (p >> 9) & 31;    // bit index
    #pragma unroll
    for (int c = 0; c < 5; ++c) {
        float v = (c < 4) ? data[c * DDIM + d]          // bb = 0
                          : structure[d] * params[d];
        unsigned bit = ((unsigned)__float_as_int(v) >> j) & 1u;
        out[(long long)SMALL + (long long)c * BIN_PER_OUT + p] = (float)(bit ^ 1u);
    }
}

extern "C" void kernel_launch(void* const* d_in, const int* in_sizes, int n_in,
                              void* d_out, int out_size, void* d_ws, size_t ws_size,
                              hipStream_t stream) {
    const float* data      = (const float*)d_in[0];
    const float* structure = (const float*)d_in[1];
    const float* params    = (const float*)d_in[2];
    const int*   nzi       = (const int*)d_in[3];
    int nnz = in_sizes[3];

    float* out = (float*)d_out;

    bins_pattern<<<SMALL, 256, 0, stream>>>(data, structure, params, out);
    bins_fixup<<<(nnz + 255) / 256, 256, 0, stream>>>(nzi, nnz, data, structure, params, out);
}

// Round 5
// 83.314 us; speedup vs baseline: 1.2815x; 1.2815x over previous
//
#include <hip/hip_runtime.h>
#include <stdint.h>

// Problem constants (from reference)
#define IN_SCALE 23
#define DDIM 529                         // 23*23
#define BATCH 2
#define BITS 32
#define HDC 512
#define ROW (BITS * HDC)                 // 16384 floats per (c,bb,d)
#define NNZ_REGION (DDIM * HDC)          // 270848 — all indices land here (bb=0, d<=16)
#define SMALL (5 * BATCH * DDIM)         // 5290 small output floats (== 2 mod 4)
#define BIN_PER_OUT (BATCH * DDIM * ROW) // 17334272
#define BIN_PER_B   (DDIM * ROW)         // 8667136
#define GPB 128                          // blocks per (c,bb) group -> grid 1280

typedef float f32x4 __attribute__((ext_vector_type(4)));

// ---------------------------------------------------------------------------
// Pattern stream, long-lived blocks: each block owns (c,bb) and loops over
// d += GPB (4-5 rows of 64KB). Regular (cached) stores — nt regressed 20%.
// Stores from successive d-iterations stay in flight together (no waitcnt
// needed on stores) -> deep store pipeline like fillBuffer's grid-stride.
// ---------------------------------------------------------------------------
__global__ __launch_bounds__(256) void bins_pattern(const float* __restrict__ data,
                                                    const float* __restrict__ structure,
                                                    const float* __restrict__ params,
                                                    float* __restrict__ out) {
    int g   = blockIdx.x / GPB;           // 0..9 == c*2+bb
    int sub = blockIdx.x % GPB;
    int c   = g >> 1;
    int bb  = g & 1;
    const int t = threadIdx.x;

    const long long gbase = (long long)SMALL + (long long)c * BIN_PER_OUT
                          + (long long)bb * BIN_PER_B;
    const int e0    = 4 * t + 2;
    const int jbase = e0 >> 9;                      // 0 or 1
    const int cross = ((e0 & 511) == 510) ? 1 : 0;  // lanes t=127,255 only

    for (int d = sub; d < DDIM; d += GPB) {
        float v;
        if (c < 4) {
            v = data[bb * (4 * DDIM) + c * DDIM + d];   // [B][4*23][23]
        } else {
            v = structure[bb * DDIM + d] * params[d];
        }
        const unsigned x = (unsigned)__float_as_int(v);
        float* o = out + gbase + (long long)d * ROW;    // == 2 (mod 4) floats

        if (t == 0) {
            out[c * (BATCH * DDIM) + bb * DDIM + d] = v;  // fused small output
            float f0 = (float)(x & 1u);                   // head: e=0,1 (bit 0)
            *(float2*)o = make_float2(f0, f0);
        } else if (t == 1) {
            float f31 = (float)(x >> 31);                 // tail: e=16382,16383 (bit 31)
            *(float2*)(o + ROW - 2) = make_float2(f31, f31);
        }

        f32x4* om = (f32x4*)(o + 2);   // 16B aligned, 4095 float4s
        unsigned xs = x >> jbase;
        #pragma unroll
        for (int k = 0; k < 16; ++k) {
            int q = t + (k << 8);
            if (q < 4095) {            // masks only lane 255 @ k=15
                float fa = (float)(xs & 1u);
                float fb = (float)((xs >> cross) & 1u);
                f32x4 w = {fa, fa, fb, fb};
                om[q] = w;
            }
            xs >>= 2;                  // bit index advances 2 per k
        }
    }
}

// ---------------------------------------------------------------------------
// Sparse fixup: for each nonzero index p (bb=0 frame, p < NNZ_REGION), the
// reference sets proj=1 -> overwrite out with bit^1 for all 5 channels.
// Duplicates idempotent. ~5.4 MB of touched lines.
// ---------------------------------------------------------------------------
__global__ __launch_bounds__(256) void bins_fixup(const int* __restrict__ idx, int n,
                                                  const float* __restrict__ data,
                                                  const float* __restrict__ structure,
                                                  const float* __restrict__ params,
                                                  float* __restrict__ out) {
    int i = blockIdx.x * blockDim.x + threadIdx.x;
    if (i >= n) return;
    unsigned p = (unsigned)idx[i];
    if (p >= NNZ_REGION) return;
    int d = p >> 14;          // p / 16384
    int j = (p >> 9) & 31;    // bit index
    #pragma unroll
    for (int c = 0; c < 5; ++c) {
        float v = (c < 4) ? data[c * DDIM + d]          // bb = 0
                          : structure[d] * params[d];
        unsigned bit = ((unsigned)__float_as_int(v) >> j) & 1u;
        out[(long long)SMALL + (long long)c * BIN_PER_OUT + p] = (float)(bit ^ 1u);
    }
}

extern "C" void kernel_launch(void* const* d_in, const int* in_sizes, int n_in,
                              void* d_out, int out_size, void* d_ws, size_t ws_size,
                              hipStream_t stream) {
    const float* data      = (const float*)d_in[0];
    const float* structure = (const float*)d_in[1];
    const float* params    = (const float*)d_in[2];
    const int*   nzi       = (const int*)d_in[3];
    int nnz = in_sizes[3];

    float* out = (float*)d_out;

    bins_pattern<<<10 * GPB, 256, 0, stream>>>(data, structure, params, out);
    bins_fixup<<<(nnz + 255) / 256, 256, 0, stream>>>(nzi, nnz, data, structure, params, out);
}

// Round 6
// 81.442 us; speedup vs baseline: 1.3110x; 1.0230x over previous
//
#include <hip/hip_runtime.h>
#include <stdint.h>

// Problem constants (from reference)
#define DDIM 529                          // 23*23
#define BATCH 2
#define BITS 32
#define HDC 512
#define ROW (BITS * HDC)                  // 16384 floats per bin-row
#define NNZ_REGION (DDIM * HDC)           // 270848 — all indices land here (bb=0, d<=16)
#define SMALL (5 * BATCH * DDIM)          // 5290 small output floats
#define BIN_PER_OUT (BATCH * DDIM * ROW)  // 17334272
#define TOTAL_FLOATS (SMALL + 5 * BIN_PER_OUT)  // 86,676,650
#define Q_BEG 1323                        // first fully-aligned float4 (float 5292)
#define Q_END (TOTAL_FLOATS / 4)          // 21,669,162 -> covers floats [5292, 86676648)

typedef float f32x4 __attribute__((ext_vector_type(4)));

// ---------------------------------------------------------------------------
// Prep: small outputs r,g,b,a,s, their bit-words xw[5290] (row words for the
// stream kernel), plus the 2 unaligned head floats (row 0 / bit 0) and the 2
// tail floats (row 5289 / bit 31). Rewritten every call (ws is poisoned).
// ---------------------------------------------------------------------------
__global__ void prep(const float* __restrict__ data,
                     const float* __restrict__ structure,
                     const float* __restrict__ params,
                     float* __restrict__ out, int* __restrict__ xw) {
    int i = blockIdx.x * blockDim.x + threadIdx.x;
    if (i >= SMALL) return;
    int c = i / 1058, rem = i % 1058, bb = rem / DDIM, d = rem % DDIM;
    float v = (c < 4) ? data[bb * (4 * DDIM) + c * DDIM + d]   // [B][4*23][23]
                      : structure[bb * DDIM + d] * params[d];
    out[i] = v;
    unsigned x = (unsigned)__float_as_int(v);
    xw[i] = (int)x;
    if (i == 0) {                        // head: bins floats 5290,5291 = row 0, bit 0
        float f = (float)(x & 1u);
        out[SMALL] = f; out[SMALL + 1] = f;
    }
    if (i == SMALL - 1) {                // tail: last 2 floats = row 5289, bit 31
        float f = (float)(x >> 31);
        out[TOTAL_FLOATS - 2] = f; out[TOTAL_FLOATS - 1] = f;
    }
}

// ---------------------------------------------------------------------------
// Flat single-frontier stream (fill-style grid-stride): one float4 per step.
// Element pairs {E0,E0+1} and {E2=E0+2,E2+1} each stay within one 512-chunk
// and one row, so two word/bit lookups cover the float4 branch-free — this
// also handles row-straddling float4s (every row boundary, since bins start
// at float 5290 == 2 mod 4).
// ---------------------------------------------------------------------------
__global__ __launch_bounds__(256) void stream4(const int* __restrict__ xw,
                                               float* __restrict__ out) {
    const unsigned nt = gridDim.x * 256u;
    f32x4* o4 = (f32x4*)out;
    for (unsigned q = Q_BEG + blockIdx.x * 256u + threadIdx.x; q < Q_END; q += nt) {
        unsigned E0 = 4u * q - SMALL;          // bins element index, == 2 mod 4
        unsigned E2 = E0 + 2u;
        unsigned w0 = (unsigned)xw[E0 >> 14];  // L1-broadcast (wave-uniform mostly)
        unsigned w1 = (unsigned)xw[E2 >> 14];
        float fa = (float)((w0 >> ((E0 & 16383u) >> 9)) & 1u);
        float fb = (float)((w1 >> ((E2 & 16383u) >> 9)) & 1u);
        f32x4 v = {fa, fa, fb, fb};
        o4[q] = v;
    }
}

// ---------------------------------------------------------------------------
// Sparse fixup: for each nonzero index p (bb=0 frame, p < NNZ_REGION), the
// reference sets proj=1 -> overwrite with bit^1 for all 5 channels.
// Duplicates idempotent. ~5.4 MB of touched lines.
// ---------------------------------------------------------------------------
__global__ void bins_fixup(const int* __restrict__ idx, int n,
                           const int* __restrict__ xw,
                           float* __restrict__ out) {
    int i = blockIdx.x * blockDim.x + threadIdx.x;
    if (i >= n) return;
    unsigned p = (unsigned)idx[i];
    if (p >= NNZ_REGION) return;
    unsigned d = p >> 14;          // row-d (0..16), bb=0
    unsigned j = (p >> 9) & 31u;   // bit index
    #pragma unroll
    for (int c = 0; c < 5; ++c) {
        unsigned w = (unsigned)xw[c * 1058 + d];   // (c, bb=0, d)
        out[(size_t)SMALL + (size_t)c * BIN_PER_OUT + p] = (float)(((w >> j) & 1u) ^ 1u);
    }
}

extern "C" void kernel_launch(void* const* d_in, const int* in_sizes, int n_in,
                              void* d_out, int out_size, void* d_ws, size_t ws_size,
                              hipStream_t stream) {
    const float* data      = (const float*)d_in[0];
    const float* structure = (const float*)d_in[1];
    const float* params    = (const float*)d_in[2];
    const int*   nzi       = (const int*)d_in[3];
    int nnz = in_sizes[3];

    float* out = (float*)d_out;
    int*   xw  = (int*)d_ws;      // 5290 int32 scratch

    prep<<<(SMALL + 255) / 256, 256, 0, stream>>>(data, structure, params, out, xw);
    stream4<<<1024, 256, 0, stream>>>(xw, out);   // 262144 threads, 4MB frontier, ~83 iters
    bins_fixup<<<(nnz + 255) / 256, 256, 0, stream>>>(nzi, nnz, xw, out);
}